// Round 7
// baseline (334.255 us; speedup 1.0000x reference)
//
#include <hip/hip_runtime.h>

#define NBATCH 8
// Per-wave tile: 54 output cols x 16 output rows.
// Lane l holds staged column bw0-5+l (64 staged cols), rows bh0-5..bh0+20
// (26 staged rows) entirely in registers.
//
// wave counts: up  (1024): 64 bands x 19 tilesX x 8 = 9728
//              x   (512):  32 bands x 10 tilesX x 8 = 2560   (cum 12288)
//              down(256):  16 bands x  5 tilesX x 8 =  640   (cum 12928)
#define NWAVES 12928
#define NBLK   (NWAVES / 4)

// ---------------------------------------------------------------------------
// 5 fused conv3x3+bias+BU+clamp iterations, all 3 levels, one dispatch.
// Pure register-resident stencil: horizontal halo via __shfl_up/__shfl_down
// (VALU pipe), vertical halo in-lane. NO LDS, NO barriers.
// Erosion: staged window rows -5..20 / lanes 0..63; iteration t computes rows
// -4..19 (all lanes); stale rim rows (0,25) and shfl-junk edge lanes corrupt
// one ring per iteration; after 5 iters rows 0..15 x lanes 5..58 are exact.
// Out-of-image cells are forced to 0 every iteration (zero-pad semantics, so
// no erosion at true image borders). All garbage is clamp-sanitized finite.
// ---------------------------------------------------------------------------
__global__ __launch_bounds__(256, 4) void conv5_all(
    const float* __restrict__ srcU, const float* __restrict__ buU,
    const float* __restrict__ wtU, const float* __restrict__ bsU,
    const float* __restrict__ srcX, const float* __restrict__ buX,
    const float* __restrict__ wtX, const float* __restrict__ bsX,
    const float* __restrict__ srcD, const float* __restrict__ buD,
    const float* __restrict__ wtD, const float* __restrict__ bsD,
    float* __restrict__ dstU, float* __restrict__ dstX, float* __restrict__ dstD)
{
    const int lane = threadIdx.x & 63;
    const int wid  = blockIdx.x * 4 + (threadIdx.x >> 6);

    const float* src; const float* BU; const float* wt; const float* bs;
    float* dst; int HW, b, tyy, txx;
    if (wid < 9728) {                       // up: 1024^2
        src = srcU; BU = buU; wt = wtU; bs = bsU; dst = dstU; HW = 1024;
        b = wid / 1216; int r = wid - b * 1216; tyy = r / 19; txx = r - tyy * 19;
    } else if (wid < 12288) {               // x: 512^2
        int t = wid - 9728;
        src = srcX; BU = buX; wt = wtX; bs = bsX; dst = dstX; HW = 512;
        b = t / 320; int r = t - b * 320; tyy = r / 10; txx = r - tyy * 10;
    } else {                                // down: 256^2
        int t = wid - 12288;
        src = srcD; BU = buD; wt = wtD; bs = bsD; dst = dstD; HW = 256;
        b = t / 80; int r = t - b * 80; tyy = r / 5; txx = r - tyy * 5;
    }
    const int bh0 = tyy << 4;
    const int bw0 = txx * 54;
    const long base = (long)b * HW * HW;
    const int gw = bw0 + lane - 5;
    const bool colok = (unsigned)gw < (unsigned)HW;

    // ---- stage 26 rows (coalesced: consecutive lanes -> consecutive cols)
    float cur[26];
    #pragma unroll
    for (int i = 0; i < 26; ++i) {
        int gh = bh0 + i - 5;
        bool ok = colok && ((unsigned)gh < (unsigned)HW);
        cur[i] = ok ? src[base + (long)gh * HW + gw] : 0.0f;
    }
    // ---- BU + bias (pre-masked) and validity mask for computed rows -4..19
    const float bias = bs[0];
    float bub[24], cm[24];
    #pragma unroll
    for (int i = 0; i < 24; ++i) {
        int gh = bh0 + i - 4;
        bool ok = colok && ((unsigned)gh < (unsigned)HW);
        cm[i]  = ok ? 1.0f : 0.0f;
        bub[i] = ok ? (BU[base + (long)gh * HW + gw] + bias) : 0.0f;
    }

    const float k00 = wt[0], k01 = wt[1], k02 = wt[2];
    const float k10 = wt[3], k11 = wt[4], k12 = wt[5];
    const float k20 = wt[6], k21 = wt[7], k22 = wt[8];

    // ---- 5 in-register conv iterations; in-place row sweep with 1-row carry
    for (int it = 0; it < 5; ++it) {
        float pm1 = cur[0];                       // old row i-1
        float Lm = __shfl_up(pm1, 1),    Rm = __shfl_down(pm1, 1);
        float Lc = __shfl_up(cur[1], 1), Rc = __shfl_down(cur[1], 1);
        #pragma unroll
        for (int i = 1; i <= 24; ++i) {
            float np = cur[i + 1];                // old row i+1
            float Lp = __shfl_up(np, 1), Rp = __shfl_down(np, 1);
            float v = bub[i - 1]
                    + k00 * Lm + k01 * pm1    + k02 * Rm
                    + k10 * Lc + k11 * cur[i] + k12 * Rc
                    + k20 * Lp + k21 * np     + k22 * Rp;
            v = fminf(1.0f, fmaxf(-1.0f, v)) * cm[i - 1];
            pm1 = cur[i];
            Lm = Lc; Rm = Rc; Lc = Lp; Rc = Rp;
            cur[i] = v;
        }
    }

    // ---- store rows 0..15 (cur[5..20]) from lanes 5..58 (54 contiguous cols)
    if (lane >= 5 && lane <= 58 && colok) {
        #pragma unroll
        for (int r = 0; r < 16; ++r)
            dst[base + (long)(bh0 + r) * HW + gw] = cur[r + 5];
    }
}

// ---------------------------------------------------------------------------
// Cross-scale 1x1-conv fusion: one thread per down-level pixel; U/X/D read
// exactly once, all three outputs written.
// ---------------------------------------------------------------------------
__global__ __launch_bounds__(256) void fuse_all(
    const float* __restrict__ X,   // 8 x 512^2
    const float* __restrict__ D,   // 8 x 256^2
    const float* __restrict__ U,   // 8 x 1024^2
    const float* __restrict__ cx,
    const float* __restrict__ cd,
    const float* __restrict__ cu,
    float* __restrict__ xo, float* __restrict__ dno, float* __restrict__ upo)
{
    const int total = NBATCH << 16;  // 8*256*256
    int idx = blockIdx.x * blockDim.x + threadIdx.x;
    if (idx >= total) return;
    int wd = idx & 255;
    int hd = (idx >> 8) & 255;
    int b  = idx >> 16;

    const float cx0 = cx[0], cx1 = cx[1], cx2 = cx[2];
    const float cd0 = cd[0], cd1 = cd[1], cd2 = cd[2];
    const float cu0 = cu[0], cu1 = cu[1], cu2 = cu[2];

    int ub = (b << 20) + ((hd << 2) << 10) + (wd << 2);
    float4 u0 = *(const float4*)&U[ub];
    float4 u1 = *(const float4*)&U[ub + 1024];
    float4 u2 = *(const float4*)&U[ub + 2048];
    float4 u3 = *(const float4*)&U[ub + 3072];
    int xb = (b << 18) + ((hd << 1) << 9) + (wd << 1);
    float2 x0 = *(const float2*)&X[xb];
    float2 x1 = *(const float2*)&X[xb + 512];
    float dv = D[idx];

    float p00 = 0.25f * (u0.x + u0.y + u1.x + u1.y);
    float p01 = 0.25f * (u0.z + u0.w + u1.z + u1.w);
    float p10 = 0.25f * (u2.x + u2.y + u3.x + u3.y);
    float p11 = 0.25f * (u2.z + u2.w + u3.z + u3.w);
    float pu4 = 0.25f * (p00 + p01 + p10 + p11);
    float px2 = 0.25f * (x0.x + x0.y + x1.x + x1.y);

    dno[idx] = cd0 * pu4 + cd1 * px2 + cd2 * dv;

    float2 xo0, xo1;
    xo0.x = cx0 * p00 + cx1 * x0.x + cx2 * dv;
    xo0.y = cx0 * p01 + cx1 * x0.y + cx2 * dv;
    xo1.x = cx0 * p10 + cx1 * x1.x + cx2 * dv;
    xo1.y = cx0 * p11 + cx1 * x1.y + cx2 * dv;
    *(float2*)&xo[xb]       = xo0;
    *(float2*)&xo[xb + 512] = xo1;

    float4 o0, o1, o2, o3;
    o0.x = cu0 * u0.x + cu1 * x0.x + cu2 * dv;
    o0.y = cu0 * u0.y + cu1 * x0.x + cu2 * dv;
    o0.z = cu0 * u0.z + cu1 * x0.y + cu2 * dv;
    o0.w = cu0 * u0.w + cu1 * x0.y + cu2 * dv;
    o1.x = cu0 * u1.x + cu1 * x0.x + cu2 * dv;
    o1.y = cu0 * u1.y + cu1 * x0.x + cu2 * dv;
    o1.z = cu0 * u1.z + cu1 * x0.y + cu2 * dv;
    o1.w = cu0 * u1.w + cu1 * x0.y + cu2 * dv;
    o2.x = cu0 * u2.x + cu1 * x1.x + cu2 * dv;
    o2.y = cu0 * u2.y + cu1 * x1.x + cu2 * dv;
    o2.z = cu0 * u2.z + cu1 * x1.y + cu2 * dv;
    o2.w = cu0 * u2.w + cu1 * x1.y + cu2 * dv;
    o3.x = cu0 * u3.x + cu1 * x1.x + cu2 * dv;
    o3.y = cu0 * u3.y + cu1 * x1.x + cu2 * dv;
    o3.z = cu0 * u3.z + cu1 * x1.y + cu2 * dv;
    o3.w = cu0 * u3.w + cu1 * x1.y + cu2 * dv;
    *(float4*)&upo[ub]        = o0;
    *(float4*)&upo[ub + 1024] = o1;
    *(float4*)&upo[ub + 2048] = o2;
    *(float4*)&upo[ub + 3072] = o3;
}

// ---------------------------------------------------------------------------
extern "C" void kernel_launch(void* const* d_in, const int* in_sizes, int n_in,
                              void* d_out, int out_size, void* d_ws, size_t ws_size,
                              hipStream_t stream)
{
    const float* x    = (const float*)d_in[0];
    const float* down = (const float*)d_in[1];
    const float* up   = (const float*)d_in[2];
    const float* BUx  = (const float*)d_in[3];
    const float* BUd  = (const float*)d_in[4];
    const float* BUu  = (const float*)d_in[5];
    const float* wAx  = (const float*)d_in[6];
    const float* bx   = (const float*)d_in[7];
    const float* wAd  = (const float*)d_in[8];
    const float* bd   = (const float*)d_in[9];
    const float* wAu  = (const float*)d_in[10];
    const float* bu   = (const float*)d_in[11];
    const float* c1x  = (const float*)d_in[12];
    const float* c1d  = (const float*)d_in[13];
    const float* c1u  = (const float*)d_in[14];

    float* out = (float*)d_out;
    float* ws  = (float*)d_ws;

    const int NX = NBATCH * 512 * 512;
    const int ND = NBATCH * 256 * 256;

    float* wsX = ws;
    float* wsD = ws + NX;
    float* wsU = ws + NX + ND;
    float* outX = out;
    float* outD = out + NX;
    float* outU = out + NX + ND;

    // one dispatch, all levels: 12928 independent waves, 4 per block
    conv5_all<<<NBLK, 256, 0, stream>>>(
        up,   BUu, wAu, bu,
        x,    BUx, wAx, bx,
        down, BUd, wAd, bd,
        wsU, wsX, wsD);

    fuse_all<<<(ND + 255) / 256, 256, 0, stream>>>(wsX, wsD, wsU, c1x, c1d, c1u,
                                                   outX, outD, outU);
}